// Round 8
// baseline (362.959 us; speedup 1.0000x reference)
//
#include <hip/hip_runtime.h>
#include <math.h>

// Problem geometry (fixed by the reference): B=32, C=16, H=W=256.
#define HW 65536
#define HW4 16384          // float4 groups per channel-plane
#define CTOT 16
#define BATCH 32
#define NPIX (BATCH * HW)  // 2,097,152 pixels per channel
#define NGRP (NPIX / 4)    // 524,288 float4 groups per channel

// Accumulator slots in workspace (double[22]); ws[22] doubles as a
// completion counter (uint) for the fused finalize.
#define NACC 22

// R7 structure (NT loads beat the dirty-L3 writeback wall: 107 -> <77 us).
// R8: finalize fused into the last-finishing block (saves one graph node).
#define GRID_BLOCKS 2048

typedef float f32x4 __attribute__((ext_vector_type(4)));

__device__ __forceinline__ float4 ldnt(const float4* p) {
    f32x4 v = __builtin_nontemporal_load((const f32x4*)p);
    float4 r; r.x = v.x; r.y = v.y; r.z = v.z; r.w = v.w;
    return r;
}

__device__ __forceinline__ float smooth_l1(float p, float g) {
    float d = fabsf(p - g);
    return (d < 1.0f) ? 0.5f * d * d : d - 0.5f;
}
// a=|x| >= 0 so 1+exp(-a) in (1,2]: plain __logf is safe (abs err < 6e-8).
__device__ __forceinline__ float bce_logits(float x, float t) {
    float e = __expf(-fabsf(x));
    return fmaxf(x, 0.0f) - x * t + __logf(1.0f + e);
}
__device__ __forceinline__ float sigmoid_fast(float x) {
    return __builtin_amdgcn_rcpf(1.0f + __expf(-x));
}
__device__ __forceinline__ float get4(const float4& v, int j) {
    return j == 0 ? v.x : (j == 1 ? v.y : (j == 2 ? v.z : v.w));
}

__global__ __launch_bounds__(256) void loss_kernel(const float* __restrict__ preds,
                                                   const float* __restrict__ gts,
                                                   double* __restrict__ ws,
                                                   float* __restrict__ out) {
    const float4* pf = (const float4*)preds;
    const float4* gf = (const float4*)gts;
    const int blk = blockIdx.x;
    const int tid = threadIdx.x;

    float acc0 = 0.0f, acc1 = 0.0f, acc2 = 0.0f;
    int base, nacc;

    if (blk < 512) {
        // ---------------- BCE task: 2 dense streams ----------------
        const int task = blk >> 7;                    // 0..3
        const int chs[4]   = {15, 14, 0, 7};
        const int bases[4] = {0, 3, 6, 9};
        const int ch = chs[task];
        base = bases[task];
        nacc = 3;
        const int lblk = blk & 127;
        const int start = lblk << 12;                 // span 4096 groups
        const int b = start >> 14;
        const int hw4s = start & (HW4 - 1);
        const size_t off = ((size_t)b * CTOT + ch) * HW4 + hw4s;
        const float4* pp = pf + off;
        const float4* gp = gf + off;
#pragma unroll 4
        for (int i = 0; i < 16; ++i) {
            const int o = (i << 8) + tid;
            float4 p = ldnt(pp + o);
            float4 t = ldnt(gp + o);
#pragma unroll
            for (int j = 0; j < 4; ++j) {
                float x  = get4(p, j);
                float tv = get4(t, j);
                float loss = bce_logits(x, tv);
                float pos  = (tv != 0.0f) ? 1.0f : 0.0f;
                acc0 += loss * pos;
                acc1 += loss * (1.0f - pos);
                acc2 += pos;
            }
        }
    } else if (blk < 1536) {
        // ---------------- displacement task: 8 dense streams ----------------
        const int task = (blk - 512) >> 9;            // 0..1
        const int c0 = task == 0 ? 1 : 8;
        base = task == 0 ? 12 : 14;
        nacc = 2;
        const int lblk = (blk - 512) & 511;
        const int start = lblk << 10;                 // span 1024 groups
        const int b = start >> 14;
        const int hw4s = start & (HW4 - 1);
        const size_t off = ((size_t)b * CTOT + c0) * HW4 + hw4s;
        const float4* pp = pf + off;
        const float4* gp = gf + off;
#pragma unroll 2
        for (int i = 0; i < 4; ++i) {
            const int o = (i << 8) + tid;
            float4 p0 = ldnt(pp + o + 0 * HW4);
            float4 p1 = ldnt(pp + o + 1 * HW4);
            float4 p2 = ldnt(pp + o + 2 * HW4);
            float4 p3 = ldnt(pp + o + 3 * HW4);
            float4 g0 = ldnt(gp + o + 0 * HW4);
            float4 g1 = ldnt(gp + o + 1 * HW4);
            float4 g2 = ldnt(gp + o + 2 * HW4);
            float4 g3 = ldnt(gp + o + 3 * HW4);
#pragma unroll
            for (int j = 0; j < 4; ++j) {
                float a0 = get4(p0, j), a1 = get4(p1, j), a2 = get4(p2, j), a3 = get4(p3, j);
                float b0 = get4(g0, j), b1 = get4(g1, j), b2 = get4(g2, j), b3 = get4(g3, j);
                float posv = fabsf(b0) + fabsf(b1) + fabsf(b2) + fabsf(b3);
                float m = (posv != 0.0f) ? 1.0f : 0.0f;
                float l1 = smooth_l1(a0, b0) + smooth_l1(a1, b1) +
                           smooth_l1(a2, b2) + smooth_l1(a3, b3);
                // swap = concat(pred[2:], pred[:2]) -> [p2,p3,p0,p1] vs gt
                float l2 = smooth_l1(a2, b0) + smooth_l1(a3, b1) +
                           smooth_l1(a0, b2) + smooth_l1(a1, b3);
                acc0 += fminf(l1, l2) * m;
                acc1 += m;
            }
        }
    } else {
        // ---------------- len/angle task: 4 dense streams ----------------
        const int task = (blk - 1536) >> 8;           // 0..1
        const int cl = task == 0 ? 5 : 12;
        base = task == 0 ? 16 : 19;
        nacc = 3;
        const int lblk = (blk - 1536) & 255;
        const int start = lblk << 11;                 // span 2048 groups
        const int b = start >> 14;
        const int hw4s = start & (HW4 - 1);
        const size_t off = ((size_t)b * CTOT + cl) * HW4 + hw4s;
        const float4* pp = pf + off;
        const float4* gp = gf + off;
#pragma unroll 2
        for (int i = 0; i < 8; ++i) {
            const int o = (i << 8) + tid;
            float4 pl = ldnt(pp + o + 0 * HW4);
            float4 pa = ldnt(pp + o + 1 * HW4);
            float4 gl = ldnt(gp + o + 0 * HW4);
            float4 ga = ldnt(gp + o + 1 * HW4);
#pragma unroll
            for (int j = 0; j < 4; ++j) {
                float glv = get4(gl, j);
                float m = (glv != 0.0f) ? 1.0f : 0.0f;
                acc0 += smooth_l1(sigmoid_fast(get4(pl, j)), glv) * m;
                acc1 += smooth_l1(sigmoid_fast(get4(pa, j)), get4(ga, j)) * m;
                acc2 += m;
            }
        }
    }

    // ---- wave (64-lane) butterfly reduce the (up to) 3 accumulators ----
#pragma unroll
    for (int off = 32; off > 0; off >>= 1) {
        acc0 += __shfl_down(acc0, off, 64);
        acc1 += __shfl_down(acc1, off, 64);
        acc2 += __shfl_down(acc2, off, 64);
    }

    __shared__ float red[4][3];
    const int lane = threadIdx.x & 63;
    const int wid  = threadIdx.x >> 6;
    if (lane == 0) { red[wid][0] = acc0; red[wid][1] = acc1; red[wid][2] = acc2; }
    __syncthreads();
    if (threadIdx.x == 0) {
        float s0 = red[0][0] + red[1][0] + red[2][0] + red[3][0];
        float s1 = red[0][1] + red[1][1] + red[2][1] + red[3][1];
        float s2 = red[0][2] + red[1][2] + red[2][2] + red[3][2];
        atomicAdd(&ws[base + 0], (double)s0);
        atomicAdd(&ws[base + 1], (double)s1);
        if (nacc == 3) atomicAdd(&ws[base + 2], (double)s2);

        // ---- fused finalize: last block to finish does the scalar math ----
        __threadfence();                               // publish our adds (device scope)
        unsigned int* cnt = (unsigned int*)(ws + NACC);
        unsigned int old = atomicAdd(cnt, 1u);
        if (old == GRID_BLOCKS - 1) {
            __threadfence();
            double v[NACC];
#pragma unroll
            for (int i = 0; i < NACC; ++i)
                v[i] = atomicAdd(&ws[i], 0.0);         // coherent device-scope read
            const double N = (double)NPIX;
            double line_seg   = v[0] / v[2]  +  1.0 * (v[1]  / (N - v[2]));
            double junc_seg   = v[3] / v[5]  + 30.0 * (v[4]  / (N - v[5]));
            double sol_center = v[6] / v[8]  + 30.0 * (v[7]  / (N - v[8]));
            double tp_center  = v[9] / v[11] + 30.0 * (v[10] / (N - v[11]));
            double sol_disp   = v[12] / v[13];
            double tp_disp    = v[14] / v[15];
            double sol_len    = v[16] / v[18];
            double sol_angle  = v[17] / v[18];
            double tp_len     = v[19] / v[21];
            double tp_angle   = v[20] / v[21];
            double total = 10.0 * tp_center + tp_disp + tp_len + tp_angle +
                           sol_center + sol_disp + sol_len + sol_angle +
                           line_seg + junc_seg;
            out[0] = (float)total;
        }
    }
}

extern "C" void kernel_launch(void* const* d_in, const int* in_sizes, int n_in,
                              void* d_out, int out_size, void* d_ws, size_t ws_size,
                              hipStream_t stream) {
    const float* preds = (const float*)d_in[0];
    const float* gts   = (const float*)d_in[1];
    double* ws = (double*)d_ws;

    // d_ws is re-poisoned to 0xAA before every launch — zero the 22
    // accumulators plus the completion counter.
    hipMemsetAsync(d_ws, 0, (NACC + 1) * sizeof(double), stream);

    loss_kernel<<<GRID_BLOCKS, 256, 0, stream>>>(preds, gts, ws, (float*)d_out);
}

// Round 9
// 278.298 us; speedup vs baseline: 1.3042x; 1.3042x over previous
//
#include <hip/hip_runtime.h>
#include <math.h>

// Problem geometry (fixed by the reference): B=32, C=16, H=W=256.
#define HW 65536
#define HW4 16384          // float4 groups per channel-plane
#define CTOT 16
#define BATCH 32
#define NPIX (BATCH * HW)  // 2,097,152 pixels per channel
#define NGRP (NPIX / 4)    // 524,288 float4 groups per channel

// Accumulator slots in workspace (double[22]) — see finalize_kernel.
#define NACC 22

// Proven best (R7): 2048 task-specialized blocks sweeping contiguous spans,
// ALL global reads NON-TEMPORAL (no L3 allocate on miss -> no forced
// eviction/writeback of the harness poison-fill's dirty Infinity-Cache
// lines during our window; this was the 107 -> <77 us win).
// R8's fused finalize REGRESSED 2x (per-block __threadfence = L2 writeback
// op x 2048, serializing at TCC) — keep the separate 1-block finalize.
#define GRID_BLOCKS 2048

typedef float f32x4 __attribute__((ext_vector_type(4)));

__device__ __forceinline__ float4 ldnt(const float4* p) {
    f32x4 v = __builtin_nontemporal_load((const f32x4*)p);
    float4 r; r.x = v.x; r.y = v.y; r.z = v.z; r.w = v.w;
    return r;
}

__device__ __forceinline__ float smooth_l1(float p, float g) {
    float d = fabsf(p - g);
    return (d < 1.0f) ? 0.5f * d * d : d - 0.5f;
}
// a=|x| >= 0 so 1+exp(-a) in (1,2]: plain __logf is safe (abs err < 6e-8).
__device__ __forceinline__ float bce_logits(float x, float t) {
    float e = __expf(-fabsf(x));
    return fmaxf(x, 0.0f) - x * t + __logf(1.0f + e);
}
__device__ __forceinline__ float sigmoid_fast(float x) {
    return __builtin_amdgcn_rcpf(1.0f + __expf(-x));
}
__device__ __forceinline__ float get4(const float4& v, int j) {
    return j == 0 ? v.x : (j == 1 ? v.y : (j == 2 ? v.z : v.w));
}

__global__ __launch_bounds__(256) void loss_kernel(const float* __restrict__ preds,
                                                   const float* __restrict__ gts,
                                                   double* __restrict__ ws) {
    const float4* pf = (const float4*)preds;
    const float4* gf = (const float4*)gts;
    const int blk = blockIdx.x;
    const int tid = threadIdx.x;

    float acc0 = 0.0f, acc1 = 0.0f, acc2 = 0.0f;
    int base, nacc;

    if (blk < 512) {
        // ---------------- BCE task: 2 dense streams ----------------
        const int task = blk >> 7;                    // 0..3
        const int chs[4]   = {15, 14, 0, 7};
        const int bases[4] = {0, 3, 6, 9};
        const int ch = chs[task];
        base = bases[task];
        nacc = 3;
        const int lblk = blk & 127;
        const int start = lblk << 12;                 // span 4096 groups
        const int b = start >> 14;
        const int hw4s = start & (HW4 - 1);
        const size_t off = ((size_t)b * CTOT + ch) * HW4 + hw4s;
        const float4* pp = pf + off;
        const float4* gp = gf + off;
#pragma unroll 4
        for (int i = 0; i < 16; ++i) {
            const int o = (i << 8) + tid;
            float4 p = ldnt(pp + o);
            float4 t = ldnt(gp + o);
#pragma unroll
            for (int j = 0; j < 4; ++j) {
                float x  = get4(p, j);
                float tv = get4(t, j);
                float loss = bce_logits(x, tv);
                float pos  = (tv != 0.0f) ? 1.0f : 0.0f;
                acc0 += loss * pos;
                acc1 += loss * (1.0f - pos);
                acc2 += pos;
            }
        }
    } else if (blk < 1536) {
        // ---------------- displacement task: 8 dense streams ----------------
        const int task = (blk - 512) >> 9;            // 0..1
        const int c0 = task == 0 ? 1 : 8;
        base = task == 0 ? 12 : 14;
        nacc = 2;
        const int lblk = (blk - 512) & 511;
        const int start = lblk << 10;                 // span 1024 groups
        const int b = start >> 14;
        const int hw4s = start & (HW4 - 1);
        const size_t off = ((size_t)b * CTOT + c0) * HW4 + hw4s;
        const float4* pp = pf + off;
        const float4* gp = gf + off;
#pragma unroll 2
        for (int i = 0; i < 4; ++i) {
            const int o = (i << 8) + tid;
            float4 p0 = ldnt(pp + o + 0 * HW4);
            float4 p1 = ldnt(pp + o + 1 * HW4);
            float4 p2 = ldnt(pp + o + 2 * HW4);
            float4 p3 = ldnt(pp + o + 3 * HW4);
            float4 g0 = ldnt(gp + o + 0 * HW4);
            float4 g1 = ldnt(gp + o + 1 * HW4);
            float4 g2 = ldnt(gp + o + 2 * HW4);
            float4 g3 = ldnt(gp + o + 3 * HW4);
#pragma unroll
            for (int j = 0; j < 4; ++j) {
                float a0 = get4(p0, j), a1 = get4(p1, j), a2 = get4(p2, j), a3 = get4(p3, j);
                float b0 = get4(g0, j), b1 = get4(g1, j), b2 = get4(g2, j), b3 = get4(g3, j);
                float posv = fabsf(b0) + fabsf(b1) + fabsf(b2) + fabsf(b3);
                float m = (posv != 0.0f) ? 1.0f : 0.0f;
                float l1 = smooth_l1(a0, b0) + smooth_l1(a1, b1) +
                           smooth_l1(a2, b2) + smooth_l1(a3, b3);
                // swap = concat(pred[2:], pred[:2]) -> [p2,p3,p0,p1] vs gt
                float l2 = smooth_l1(a2, b0) + smooth_l1(a3, b1) +
                           smooth_l1(a0, b2) + smooth_l1(a1, b3);
                acc0 += fminf(l1, l2) * m;
                acc1 += m;
            }
        }
    } else {
        // ---------------- len/angle task: 4 dense streams ----------------
        const int task = (blk - 1536) >> 8;           // 0..1
        const int cl = task == 0 ? 5 : 12;
        base = task == 0 ? 16 : 19;
        nacc = 3;
        const int lblk = (blk - 1536) & 255;
        const int start = lblk << 11;                 // span 2048 groups
        const int b = start >> 14;
        const int hw4s = start & (HW4 - 1);
        const size_t off = ((size_t)b * CTOT + cl) * HW4 + hw4s;
        const float4* pp = pf + off;
        const float4* gp = gf + off;
#pragma unroll 2
        for (int i = 0; i < 8; ++i) {
            const int o = (i << 8) + tid;
            float4 pl = ldnt(pp + o + 0 * HW4);
            float4 pa = ldnt(pp + o + 1 * HW4);
            float4 gl = ldnt(gp + o + 0 * HW4);
            float4 ga = ldnt(gp + o + 1 * HW4);
#pragma unroll
            for (int j = 0; j < 4; ++j) {
                float glv = get4(gl, j);
                float m = (glv != 0.0f) ? 1.0f : 0.0f;
                acc0 += smooth_l1(sigmoid_fast(get4(pl, j)), glv) * m;
                acc1 += smooth_l1(sigmoid_fast(get4(pa, j)), get4(ga, j)) * m;
                acc2 += m;
            }
        }
    }

    // ---- wave (64-lane) butterfly reduce the (up to) 3 accumulators ----
#pragma unroll
    for (int off = 32; off > 0; off >>= 1) {
        acc0 += __shfl_down(acc0, off, 64);
        acc1 += __shfl_down(acc1, off, 64);
        acc2 += __shfl_down(acc2, off, 64);
    }

    __shared__ float red[4][3];
    const int lane = threadIdx.x & 63;
    const int wid  = threadIdx.x >> 6;
    if (lane == 0) { red[wid][0] = acc0; red[wid][1] = acc1; red[wid][2] = acc2; }
    __syncthreads();
    if (threadIdx.x == 0) {
        float s0 = red[0][0] + red[1][0] + red[2][0] + red[3][0];
        float s1 = red[0][1] + red[1][1] + red[2][1] + red[3][1];
        float s2 = red[0][2] + red[1][2] + red[2][2] + red[3][2];
        atomicAdd(&ws[base + 0], (double)s0);
        atomicAdd(&ws[base + 1], (double)s1);
        if (nacc == 3) atomicAdd(&ws[base + 2], (double)s2);
    }
}

__global__ void finalize_kernel(const double* __restrict__ ws, float* __restrict__ out) {
    if (threadIdx.x == 0 && blockIdx.x == 0) {
        const double N = (double)NPIX;
        double line_seg   = ws[0] / ws[2]  +  1.0 * (ws[1]  / (N - ws[2]));
        double junc_seg   = ws[3] / ws[5]  + 30.0 * (ws[4]  / (N - ws[5]));
        double sol_center = ws[6] / ws[8]  + 30.0 * (ws[7]  / (N - ws[8]));
        double tp_center  = ws[9] / ws[11] + 30.0 * (ws[10] / (N - ws[11]));
        double sol_disp   = ws[12] / ws[13];
        double tp_disp    = ws[14] / ws[15];
        double sol_len    = ws[16] / ws[18];
        double sol_angle  = ws[17] / ws[18];
        double tp_len     = ws[19] / ws[21];
        double tp_angle   = ws[20] / ws[21];
        double total = 10.0 * tp_center + tp_disp + tp_len + tp_angle +
                       sol_center + sol_disp + sol_len + sol_angle +
                       line_seg + junc_seg;
        out[0] = (float)total;
    }
}

extern "C" void kernel_launch(void* const* d_in, const int* in_sizes, int n_in,
                              void* d_out, int out_size, void* d_ws, size_t ws_size,
                              hipStream_t stream) {
    const float* preds = (const float*)d_in[0];
    const float* gts   = (const float*)d_in[1];
    double* ws = (double*)d_ws;

    // d_ws is re-poisoned to 0xAA before every launch — zero the accumulators.
    hipMemsetAsync(d_ws, 0, NACC * sizeof(double), stream);

    loss_kernel<<<GRID_BLOCKS, 256, 0, stream>>>(preds, gts, ws);
    finalize_kernel<<<1, 64, 0, stream>>>(ws, (float*)d_out);
}